// Round 1
// baseline (157.316 us; speedup 1.0000x reference)
//
#include <hip/hip_runtime.h>

#define BQ 32
#define S  32
#define H  128
#define C  512
#define D  128

typedef short short8 __attribute__((ext_vector_type(8)));
typedef float floatx4 __attribute__((ext_vector_type(4)));
typedef unsigned short ushort4v __attribute__((ext_vector_type(4)));

__device__ __forceinline__ unsigned short f2bf(float x) {
  unsigned int u = __float_as_uint(x);
  u += 0x7FFFu + ((u >> 16) & 1u);   // RNE
  return (unsigned short)(u >> 16);
}
__device__ __forceinline__ float bf2f(unsigned short b) {
  return __uint_as_float(((unsigned int)b) << 16);
}

// ---------------------------------------------------------------------------
// Kernel 0: split Q (fp32) into bf16 hi/lo, stored in MFMA A-fragment order.
// Layout (16-bit units): ((((b*4 + kb)*2 + mt)*2 + sel)*64 + lane)*8 + j
//   lane = quad*16 + (s&15), k = kb*32 + quad*8 + j   (A[m=lane&15][k=quad*8+j])
// ---------------------------------------------------------------------------
__global__ __launch_bounds__(256) void qsplit_kernel(const float* __restrict__ q,
                                                     unsigned short* __restrict__ qs) {
  int f = blockIdx.x * 256 + threadIdx.x;       // float4 index, 0..32767
  const float4* q4 = (const float4*)q;
  float4 v = q4[f];
  int b   = f >> 10;
  int rem = f & 1023;
  int s   = rem >> 5;
  int h   = (rem & 31) * 4;
  int mt = s >> 4, mi = s & 15;
  int kb = h >> 5, quad = (h >> 3) & 3, j0 = h & 7;
  int lane = quad * 16 + mi;
  int base = ((((b * 4 + kb) * 2 + mt) * 2 + 0) * 64 + lane) * 8 + j0;
  float xs[4] = {v.x, v.y, v.z, v.w};
  ushort4v hi, lo;
#pragma unroll
  for (int j = 0; j < 4; ++j) {
    unsigned short hb = f2bf(xs[j]);
    hi[j] = hb;
    lo[j] = f2bf(xs[j] - bf2f(hb));
  }
  *(ushort4v*)&qs[base]       = hi;
  *(ushort4v*)&qs[base + 512] = lo;   // sel=1 plane is +64*8 elements
}

// ---------------------------------------------------------------------------
// Kernel 1: per block c, compute scores[b][c] = 50 * sum_s max_d (Q_b . P_c^T)
// Wave w: mtile = w&1 (s rows), ntiles (w>>1)*4 .. +3 (d cols).
// P_c fragments (bf16 hi/lo) are register-resident for all 32 b iterations.
// ---------------------------------------------------------------------------
__global__ __launch_bounds__(256, 2) void scores_kernel(const float* __restrict__ pos,
                                                        const unsigned short* __restrict__ qs,
                                                        float* __restrict__ scores) {
  const int c    = blockIdx.x;
  const int tid  = threadIdx.x;
  const int w    = tid >> 6;
  const int lane = tid & 63;
  const int mt   = w & 1;
  const int ntg  = (w >> 1) * 4;
  const int quad = lane >> 4;
  const int nrow = lane & 15;

  __shared__ float pm[4][32];

  // ---- one-time: load P_c fragments straight from global, split hi/lo ----
  short8 bh[4][4], bl[4][4];   // [nt][kb]
  {
    const float* pc = pos + (size_t)c * (D * H);
#pragma unroll
    for (int nt = 0; nt < 4; ++nt) {
      int d = (ntg + nt) * 16 + nrow;          // B-frag: n = lane&15
#pragma unroll
      for (int kb = 0; kb < 4; ++kb) {
        const float* src = pc + d * H + kb * 32 + quad * 8;   // k = quad*8 + j
        float4 v0 = *(const float4*)(src);
        float4 v1 = *(const float4*)(src + 4);
        float xs[8] = {v0.x, v0.y, v0.z, v0.w, v1.x, v1.y, v1.z, v1.w};
        short8 fh, fl;
#pragma unroll
        for (int j = 0; j < 8; ++j) {
          unsigned short hb = f2bf(xs[j]);
          fh[j] = (short)hb;
          fl[j] = (short)f2bf(xs[j] - bf2f(hb));
        }
        bh[nt][kb] = fh;
        bl[nt][kb] = fl;
      }
    }
  }

  const short8* qf = (const short8*)qs;

  for (int b = 0; b < BQ; ++b) {
    floatx4 acc[4];
#pragma unroll
    for (int nt = 0; nt < 4; ++nt) {
      floatx4 z = {0.f, 0.f, 0.f, 0.f};
      acc[nt] = z;
    }

#pragma unroll
    for (int kb = 0; kb < 4; ++kb) {
      int ai = (((b * 4 + kb) * 2 + mt) * 2) * 64 + lane;
      short8 ah = qf[ai];
      short8 al = qf[ai + 64];
#pragma unroll
      for (int nt = 0; nt < 4; ++nt)
        acc[nt] = __builtin_amdgcn_mfma_f32_16x16x32_bf16(ah, bh[nt][kb], acc[nt], 0, 0, 0);
#pragma unroll
      for (int nt = 0; nt < 4; ++nt)
        acc[nt] = __builtin_amdgcn_mfma_f32_16x16x32_bf16(ah, bl[nt][kb], acc[nt], 0, 0, 0);
#pragma unroll
      for (int nt = 0; nt < 4; ++nt)
        acc[nt] = __builtin_amdgcn_mfma_f32_16x16x32_bf16(al, bh[nt][kb], acc[nt], 0, 0, 0);
    }

    // C/D layout: col(d) = lane&15, row(s_local) = quad*4 + reg  [m89/m91]
    // max over this wave's 64 d for each of its 16 s rows
    float m[4];
#pragma unroll
    for (int r = 0; r < 4; ++r)
      m[r] = fmaxf(fmaxf(acc[0][r], acc[1][r]), fmaxf(acc[2][r], acc[3][r]));
#pragma unroll
    for (int r = 0; r < 4; ++r) {
      m[r] = fmaxf(m[r], __shfl_xor(m[r], 1));
      m[r] = fmaxf(m[r], __shfl_xor(m[r], 2));
      m[r] = fmaxf(m[r], __shfl_xor(m[r], 4));
      m[r] = fmaxf(m[r], __shfl_xor(m[r], 8));
    }
    if (nrow == 0) {
#pragma unroll
      for (int r = 0; r < 4; ++r)
        pm[w][mt * 16 + quad * 4 + r] = m[r];
    }
    __syncthreads();
    if (tid < 32) {
      int s = tid;
      int mtc = s >> 4;
      float v = fmaxf(pm[mtc][s], pm[mtc + 2][s]);   // waves {mtc, mtc+2} own s
      v += __shfl_xor(v, 1, 32);
      v += __shfl_xor(v, 2, 32);
      v += __shfl_xor(v, 4, 32);
      v += __shfl_xor(v, 8, 32);
      v += __shfl_xor(v, 16, 32);
      if (s == 0) scores[b * C + c] = v * 50.0f;     // / TEMPERATURE
    }
    __syncthreads();
  }
}

// ---------------------------------------------------------------------------
// Kernel 2: loss = mean_b( logsumexp_c(scores[b,:]) - scores[b,0] )
// ---------------------------------------------------------------------------
__global__ __launch_bounds__(256) void loss_kernel(const float* __restrict__ scores,
                                                   float* __restrict__ out) {
  __shared__ float part[4];
  int tid = threadIdx.x, w = tid >> 6, lane = tid & 63;
  float lsum = 0.f;
  for (int b = w * 8; b < w * 8 + 8; ++b) {
    const float* row = scores + b * C;
    float x[8];
    float mx = -3.4e38f;
#pragma unroll
    for (int k = 0; k < 8; ++k) {
      x[k] = row[lane + 64 * k];
      mx = fmaxf(mx, x[k]);
    }
#pragma unroll
    for (int off = 1; off < 64; off <<= 1) mx = fmaxf(mx, __shfl_xor(mx, off));
    float e = 0.f;
#pragma unroll
    for (int k = 0; k < 8; ++k) e += expf(x[k] - mx);
#pragma unroll
    for (int off = 1; off < 64; off <<= 1) e += __shfl_xor(e, off);
    if (lane == 0) lsum += (mx + logf(e)) - row[0];
  }
  if (lane == 0) part[w] = lsum;
  __syncthreads();
  if (tid == 0) out[0] = (part[0] + part[1] + part[2] + part[3]) * (1.0f / 32.0f);
}

extern "C" void kernel_launch(void* const* d_in, const int* in_sizes, int n_in,
                              void* d_out, int out_size, void* d_ws, size_t ws_size,
                              hipStream_t stream) {
  const float* q = (const float*)d_in[0];   // [32,32,128] fp32
  const float* p = (const float*)d_in[1];   // [512,128,128] fp32
  float* scores = (float*)d_ws;                               // 32*512 fp32 = 64 KB
  unsigned short* qs = (unsigned short*)((char*)d_ws + 65536); // 512 KB bf16 hi/lo frags

  qsplit_kernel<<<128, 256, 0, stream>>>(q, qs);
  scores_kernel<<<C, 256, 0, stream>>>(p, qs, scores);
  loss_kernel<<<1, 256, 0, stream>>>(scores, (float*)d_out);
}

// Round 2
// 102.133 us; speedup vs baseline: 1.5403x; 1.5403x over previous
//
#include <hip/hip_runtime.h>

#define BQ 32
#define H  128
#define C  512
#define D  128

typedef _Float16 half8v __attribute__((ext_vector_type(8)));
typedef float floatx4 __attribute__((ext_vector_type(4)));

// ---------------------------------------------------------------------------
// Kernel 0: Q fp32 -> fp16 MFMA A-fragments (coalesced 16B stores), and zero
// the loss accumulator (d_out) so the loss kernel can atomicAdd into it.
// Fragment index (half8 units): ((b*4 + kb)*2 + mt)*64 + lane
//   lane = quad*16 + (s&15);  A[m = lane&15][k = kb*32 + quad*8 + j]
// ---------------------------------------------------------------------------
__global__ __launch_bounds__(256) void qprep_kernel(const float* __restrict__ q,
                                                    _Float16* __restrict__ qs,
                                                    float* __restrict__ out) {
  int t = blockIdx.x * 256 + threadIdx.x;     // 0..16383, one half8 frag each
  if (t == 0) out[0] = 0.0f;
  int lane = t & 63;
  int mt   = (t >> 6) & 1;
  int kb   = (t >> 7) & 3;
  int b    = t >> 9;
  int s    = mt * 16 + (lane & 15);
  int h    = kb * 32 + (lane >> 4) * 8;
  const float* src = q + ((b * 32 + s) * H + h);
  float4 v0 = *(const float4*)src;
  float4 v1 = *(const float4*)(src + 4);
  half8v o = { (_Float16)v0.x, (_Float16)v0.y, (_Float16)v0.z, (_Float16)v0.w,
               (_Float16)v1.x, (_Float16)v1.y, (_Float16)v1.z, (_Float16)v1.w };
  *(half8v*)(qs + (size_t)t * 8) = o;
}

// ---------------------------------------------------------------------------
// Kernel 1: block c -> scores[b][c] = 50 * sum_s max_d (Q_b . P_c^T), fp16 MFMA.
// Wave w: s-tile mt=w&1 (16 rows), d-range (w>>1)*64 .. +63 (ntiles ntg..ntg+3).
// P_c fragments register-resident (64 VGPRs). No barrier inside the b-loop.
// ---------------------------------------------------------------------------
__global__ __launch_bounds__(256, 2) void scores_kernel(const float* __restrict__ pos,
                                                        const _Float16* __restrict__ qs,
                                                        float* __restrict__ scores) {
  const int c    = blockIdx.x;
  const int tid  = threadIdx.x;
  const int w    = tid >> 6;
  const int lane = tid & 63;
  const int mt   = w & 1;
  const int half = w >> 1;
  const int ntg  = half * 4;
  const int quad = lane >> 4;
  const int nrow = lane & 15;

  __shared__ float pmm[BQ][2][32];   // [b][d-half][s]  8 KB

  // ---- one-time: load P_c straight from global, convert to fp16 B-frags ----
  half8v bf[4][4];   // [nt][kb]
  {
    const float* pc = pos + (size_t)c * (D * H);
#pragma unroll
    for (int nt = 0; nt < 4; ++nt) {
      int d = (ntg + nt) * 16 + nrow;                       // B-frag: n = lane&15
#pragma unroll
      for (int kb = 0; kb < 4; ++kb) {
        const float* src = pc + d * H + kb * 32 + quad * 8; // k = quad*8 + j
        float4 v0 = *(const float4*)src;
        float4 v1 = *(const float4*)(src + 4);
        half8v f = { (_Float16)v0.x, (_Float16)v0.y, (_Float16)v0.z, (_Float16)v0.w,
                     (_Float16)v1.x, (_Float16)v1.y, (_Float16)v1.z, (_Float16)v1.w };
        bf[nt][kb] = f;
      }
    }
  }

  const half8v* qf = (const half8v*)qs;
  const int abase = mt * 64 + lane;          // + b*512 + kb*128

  half8v a[4];
#pragma unroll
  for (int kb = 0; kb < 4; ++kb) a[kb] = qf[abase + kb * 128];   // b = 0

  for (int b = 0; b < BQ; ++b) {
    // prefetch next b's A-fragments
    half8v an[4];
    if (b < BQ - 1) {
      int nb = (b + 1) * 512 + abase;
#pragma unroll
      for (int kb = 0; kb < 4; ++kb) an[kb] = qf[nb + kb * 128];
    }

    floatx4 acc[4];
#pragma unroll
    for (int nt = 0; nt < 4; ++nt) { floatx4 z = {0.f, 0.f, 0.f, 0.f}; acc[nt] = z; }

#pragma unroll
    for (int kb = 0; kb < 4; ++kb)
#pragma unroll
      for (int nt = 0; nt < 4; ++nt)
        acc[nt] = __builtin_amdgcn_mfma_f32_16x16x32_f16(a[kb], bf[nt][kb], acc[nt], 0, 0, 0);

    // C/D layout: d = nt*16 + (lane&15) + ntg*16 ; s_local = quad*4 + r  [m89/m91]
    float m0 = fmaxf(fmaxf(acc[0][0], acc[1][0]), fmaxf(acc[2][0], acc[3][0]));
    float m1 = fmaxf(fmaxf(acc[0][1], acc[1][1]), fmaxf(acc[2][1], acc[3][1]));
    float m2 = fmaxf(fmaxf(acc[0][2], acc[1][2]), fmaxf(acc[2][2], acc[3][2]));
    float m3 = fmaxf(fmaxf(acc[0][3], acc[1][3]), fmaxf(acc[2][3], acc[3][3]));
#pragma unroll
    for (int off = 1; off < 16; off <<= 1) {
      m0 = fmaxf(m0, __shfl_xor(m0, off));
      m1 = fmaxf(m1, __shfl_xor(m1, off));
      m2 = fmaxf(m2, __shfl_xor(m2, off));
      m3 = fmaxf(m3, __shfl_xor(m3, off));
    }
    if (nrow == 0) {
      float4 v = {m0, m1, m2, m3};
      *(float4*)&pmm[b][half][mt * 16 + quad * 4] = v;
    }

#pragma unroll
    for (int kb = 0; kb < 4; ++kb) a[kb] = an[kb];
  }

  __syncthreads();

  // epilogue: scores[b][c] = 50 * sum_s max(half0, half1)
  {
    int b  = tid >> 3;
    int sq = tid & 7;
    float4 x = *(float4*)&pmm[b][0][sq * 4];
    float4 y = *(float4*)&pmm[b][1][sq * 4];
    float v = fmaxf(x.x, y.x) + fmaxf(x.y, y.y) + fmaxf(x.z, y.z) + fmaxf(x.w, y.w);
    v += __shfl_xor(v, 1);
    v += __shfl_xor(v, 2);
    v += __shfl_xor(v, 4);
    if ((tid & 7) == 0) scores[b * C + c] = v * 50.0f;   // / TEMPERATURE
  }
}

// ---------------------------------------------------------------------------
// Kernel 2: one block per b; loss += (logsumexp_c - scores[b][0]) / 32
// ---------------------------------------------------------------------------
__global__ __launch_bounds__(256) void loss_kernel(const float* __restrict__ scores,
                                                   float* __restrict__ out) {
  __shared__ float red[8];
  const int b = blockIdx.x, tid = threadIdx.x, w = tid >> 6, lane = tid & 63;
  const float* row = scores + b * C;
  float x0 = row[tid], x1 = row[tid + 256];
  float mx = fmaxf(x0, x1);
#pragma unroll
  for (int off = 1; off < 64; off <<= 1) mx = fmaxf(mx, __shfl_xor(mx, off));
  if (lane == 0) red[w] = mx;
  __syncthreads();
  float bmax = fmaxf(fmaxf(red[0], red[1]), fmaxf(red[2], red[3]));
  float e = __expf(x0 - bmax) + __expf(x1 - bmax);
#pragma unroll
  for (int off = 1; off < 64; off <<= 1) e += __shfl_xor(e, off);
  if (lane == 0) red[4 + w] = e;
  __syncthreads();
  if (tid == 0) {
    float s = red[4] + red[5] + red[6] + red[7];
    atomicAdd(out, (bmax + __logf(s) - row[0]) * (1.0f / 32.0f));
  }
}

extern "C" void kernel_launch(void* const* d_in, const int* in_sizes, int n_in,
                              void* d_out, int out_size, void* d_ws, size_t ws_size,
                              hipStream_t stream) {
  const float* q = (const float*)d_in[0];   // [32,32,128] fp32
  const float* p = (const float*)d_in[1];   // [512,128,128] fp32
  float* scores  = (float*)d_ws;                              // 64 KB
  _Float16* qs   = (_Float16*)((char*)d_ws + 65536);          // 256 KB fp16 A-frags

  qprep_kernel<<<64, 256, 0, stream>>>(q, qs, (float*)d_out);
  scores_kernel<<<C, 256, 0, stream>>>(p, qs, scores);
  loss_kernel<<<32, 256, 0, stream>>>(scores, (float*)d_out);
}

// Round 3
// 99.640 us; speedup vs baseline: 1.5788x; 1.0250x over previous
//
#include <hip/hip_runtime.h>

#define BQ 32
#define H  128
#define C  512
#define D  128

typedef _Float16 half8v __attribute__((ext_vector_type(8)));
typedef float floatx4 __attribute__((ext_vector_type(4)));

// ---------------------------------------------------------------------------
// Kernel 0: Q fp32 -> fp16 MFMA A-fragments (coalesced 16B stores), and zero
// the loss accumulator (d_out) so the loss kernel can atomicAdd into it.
// Fragment index (half8 units): ((b*4 + kb)*2 + mt)*64 + lane
//   lane = quad*16 + (s&15);  A[m = lane&15][k = kb*32 + quad*8 + j]
// ---------------------------------------------------------------------------
__global__ __launch_bounds__(256) void qprep_kernel(const float* __restrict__ q,
                                                    _Float16* __restrict__ qs,
                                                    float* __restrict__ out) {
  int t = blockIdx.x * 256 + threadIdx.x;     // 0..16383, one half8 frag each
  if (t == 0) out[0] = 0.0f;
  int lane = t & 63;
  int mt   = (t >> 6) & 1;
  int kb   = (t >> 7) & 3;
  int b    = t >> 9;
  int s    = mt * 16 + (lane & 15);
  int h    = kb * 32 + (lane >> 4) * 8;
  const float* src = q + ((b * 32 + s) * H + h);
  float4 v0 = *(const float4*)src;
  float4 v1 = *(const float4*)(src + 4);
  half8v o = { (_Float16)v0.x, (_Float16)v0.y, (_Float16)v0.z, (_Float16)v0.w,
               (_Float16)v1.x, (_Float16)v1.y, (_Float16)v1.z, (_Float16)v1.w };
  *(half8v*)(qs + (size_t)t * 8) = o;
}

// ---------------------------------------------------------------------------
// Kernel 1: block c -> scores[b][c] = 50 * sum_s max_d (Q_b . P_c^T), fp16 MFMA.
// Wave w: s-tile mt=w&1 (16 rows), d-range (w>>1)*64 (ntiles ntg..ntg+3).
// Software-pipelined: two acc sets so the shuffle reduction of iteration b
// overlaps the MFMA burst of iteration b+1; kb-major B loads so b=0 MFMAs
// start while P-tile loads for kb=1..3 are still in flight.
// ---------------------------------------------------------------------------
__global__ __launch_bounds__(256, 2) void scores_kernel(const float* __restrict__ pos,
                                                        const _Float16* __restrict__ qs,
                                                        float* __restrict__ scores) {
  const int c    = blockIdx.x;
  const int tid  = threadIdx.x;
  const int w    = tid >> 6;
  const int lane = tid & 63;
  const int mt   = w & 1;
  const int half = w >> 1;
  const int ntg  = half * 4;
  const int quad = lane >> 4;
  const int nrow = lane & 15;

  __shared__ float pmm[BQ][2][32];   // [b][d-half][s]  8 KB

  const half8v* qf = (const half8v*)qs;
  const int abase  = mt * 64 + lane;          // + b*512 + kb*128
  const float* pc  = pos + (size_t)c * (D * H);

  half8v  bf[4][4];     // [kb][nt]  P_c fragments, register-resident (64 VGPRs)
  half8v  areg[2][4];   // double-buffered A fragments [buf][kb]
  floatx4 acc[2][4];    // double-buffered accumulators [buf][nt]

  // A fragments for b=0 and b=1
#pragma unroll
  for (int kb = 0; kb < 4; ++kb) areg[0][kb] = qf[abase + kb * 128];
#pragma unroll
  for (int kb = 0; kb < 4; ++kb) areg[1][kb] = qf[512 + abase + kb * 128];

  // P_c fragments, kb-major (B-frag: n = lane&15, k = quad*8 + j)
#pragma unroll
  for (int kb = 0; kb < 4; ++kb)
#pragma unroll
    for (int nt = 0; nt < 4; ++nt) {
      const float* src = pc + ((ntg + nt) * 16 + nrow) * H + kb * 32 + quad * 8;
      float4 v0 = *(const float4*)src;
      float4 v1 = *(const float4*)(src + 4);
      half8v f = { (_Float16)v0.x, (_Float16)v0.y, (_Float16)v0.z, (_Float16)v0.w,
                   (_Float16)v1.x, (_Float16)v1.y, (_Float16)v1.z, (_Float16)v1.w };
      bf[kb][nt] = f;
    }

  // reduction + LDS store for a finished accumulator
  // C/D layout: d = (ntg+nt)*16 + (lane&15); s_local = quad*4 + r  [m89/m91]
  auto reduce_store = [&](int b, floatx4* a) {
    float m0 = fmaxf(fmaxf(a[0][0], a[1][0]), fmaxf(a[2][0], a[3][0]));
    float m1 = fmaxf(fmaxf(a[0][1], a[1][1]), fmaxf(a[2][1], a[3][1]));
    float m2 = fmaxf(fmaxf(a[0][2], a[1][2]), fmaxf(a[2][2], a[3][2]));
    float m3 = fmaxf(fmaxf(a[0][3], a[1][3]), fmaxf(a[2][3], a[3][3]));
#pragma unroll
    for (int off = 1; off < 16; off <<= 1) {
      m0 = fmaxf(m0, __shfl_xor(m0, off));
      m1 = fmaxf(m1, __shfl_xor(m1, off));
      m2 = fmaxf(m2, __shfl_xor(m2, off));
      m3 = fmaxf(m3, __shfl_xor(m3, off));
    }
    if (nrow == 0) {
      float4 v = {m0, m1, m2, m3};
      *(float4*)&pmm[b][half][mt * 16 + quad * 4] = v;
    }
  };

  // b = 0 into acc[0] (overlaps the tail of the bf loads via fine vmcnt)
#pragma unroll
  for (int nt = 0; nt < 4; ++nt) { floatx4 z = {0.f, 0.f, 0.f, 0.f}; acc[0][nt] = z; }
#pragma unroll
  for (int kb = 0; kb < 4; ++kb)
#pragma unroll
    for (int nt = 0; nt < 4; ++nt)
      acc[0][nt] = __builtin_amdgcn_mfma_f32_16x16x32_f16(areg[0][kb], bf[kb][nt], acc[0][nt], 0, 0, 0);

  // pipelined main loop: MFMAs for b overlap reduction of b-1
#pragma unroll
  for (int b = 1; b < BQ; ++b) {
    const int cur = b & 1, prv = cur ^ 1;
    if (b + 1 < BQ) {
      const int nb = (b + 1) * 512 + abase;
#pragma unroll
      for (int kb = 0; kb < 4; ++kb) areg[prv][kb] = qf[nb + kb * 128];
    }
#pragma unroll
    for (int nt = 0; nt < 4; ++nt) { floatx4 z = {0.f, 0.f, 0.f, 0.f}; acc[cur][nt] = z; }
#pragma unroll
    for (int kb = 0; kb < 4; ++kb)
#pragma unroll
      for (int nt = 0; nt < 4; ++nt)
        acc[cur][nt] = __builtin_amdgcn_mfma_f32_16x16x32_f16(areg[cur][kb], bf[kb][nt], acc[cur][nt], 0, 0, 0);
    reduce_store(b - 1, acc[prv]);
  }
  reduce_store(BQ - 1, acc[1]);   // b=31 landed in acc[31&1]

  __syncthreads();

  // epilogue: scores[b][c] = 50 * sum_s max(half0, half1)
  {
    int b  = tid >> 3;
    int sq = tid & 7;
    float4 x = *(float4*)&pmm[b][0][sq * 4];
    float4 y = *(float4*)&pmm[b][1][sq * 4];
    float v = fmaxf(x.x, y.x) + fmaxf(x.y, y.y) + fmaxf(x.z, y.z) + fmaxf(x.w, y.w);
    v += __shfl_xor(v, 1);
    v += __shfl_xor(v, 2);
    v += __shfl_xor(v, 4);
    if ((tid & 7) == 0) scores[b * C + c] = v * 50.0f;   // / TEMPERATURE
  }
}

// ---------------------------------------------------------------------------
// Kernel 2: one block per b; loss += (logsumexp_c - scores[b][0]) / 32
// ---------------------------------------------------------------------------
__global__ __launch_bounds__(256) void loss_kernel(const float* __restrict__ scores,
                                                   float* __restrict__ out) {
  __shared__ float red[8];
  const int b = blockIdx.x, tid = threadIdx.x, w = tid >> 6, lane = tid & 63;
  const float* row = scores + b * C;
  float x0 = row[tid], x1 = row[tid + 256];
  float mx = fmaxf(x0, x1);
#pragma unroll
  for (int off = 1; off < 64; off <<= 1) mx = fmaxf(mx, __shfl_xor(mx, off));
  if (lane == 0) red[w] = mx;
  __syncthreads();
  float bmax = fmaxf(fmaxf(red[0], red[1]), fmaxf(red[2], red[3]));
  float e = __expf(x0 - bmax) + __expf(x1 - bmax);
#pragma unroll
  for (int off = 1; off < 64; off <<= 1) e += __shfl_xor(e, off);
  if (lane == 0) red[4 + w] = e;
  __syncthreads();
  if (tid == 0) {
    float s = red[4] + red[5] + red[6] + red[7];
    atomicAdd(out, (bmax + __logf(s) - row[0]) * (1.0f / 32.0f));
  }
}

extern "C" void kernel_launch(void* const* d_in, const int* in_sizes, int n_in,
                              void* d_out, int out_size, void* d_ws, size_t ws_size,
                              hipStream_t stream) {
  const float* q = (const float*)d_in[0];   // [32,32,128] fp32
  const float* p = (const float*)d_in[1];   // [512,128,128] fp32
  float* scores  = (float*)d_ws;                              // 64 KB
  _Float16* qs   = (_Float16*)((char*)d_ws + 65536);          // 256 KB fp16 A-frags

  qprep_kernel<<<64, 256, 0, stream>>>(q, qs, (float*)d_out);
  scores_kernel<<<C, 256, 0, stream>>>(p, qs, scores);
  loss_kernel<<<32, 256, 0, stream>>>(scores, (float*)d_out);
}

// Round 4
// 96.469 us; speedup vs baseline: 1.6307x; 1.0329x over previous
//
#include <hip/hip_runtime.h>

#define BQ 32
#define H  128
#define C  512
#define D  128

typedef _Float16 half8v __attribute__((ext_vector_type(8)));
typedef float floatx4 __attribute__((ext_vector_type(4)));

// ---------------------------------------------------------------------------
// Kernel 0: Q fp32 -> fp16 MFMA fragments (coalesced 16B stores), and zero the
// loss accumulator (d_out) for the loss kernel's atomicAdd.
// Fragment index (half8 units): ((b*4 + kb)*2 + st)*64 + lane
//   lane = quad*16 + (s&15);  elem[n = lane&15][k = kb*32 + quad*8 + j]
// This is simultaneously a valid A-frag (m=lane&15) and B-frag (n=lane&15).
// ---------------------------------------------------------------------------
__global__ __launch_bounds__(256) void qprep_kernel(const float* __restrict__ q,
                                                    _Float16* __restrict__ qs,
                                                    float* __restrict__ out) {
  int t = blockIdx.x * 256 + threadIdx.x;     // 0..16383, one half8 frag each
  if (t == 0) out[0] = 0.0f;
  int lane = t & 63;
  int st   = (t >> 6) & 1;
  int kb   = (t >> 7) & 3;
  int b    = t >> 9;
  int s    = st * 16 + (lane & 15);
  int h    = kb * 32 + (lane >> 4) * 8;
  const float* src = q + ((b * 32 + s) * H + h);
  float4 v0 = *(const float4*)src;
  float4 v1 = *(const float4*)(src + 4);
  half8v o = { (_Float16)v0.x, (_Float16)v0.y, (_Float16)v0.z, (_Float16)v0.w,
               (_Float16)v1.x, (_Float16)v1.y, (_Float16)v1.z, (_Float16)v1.w };
  *(half8v*)(qs + (size_t)t * 8) = o;
}

// ---------------------------------------------------------------------------
// Kernel 1: block c -> scores[b][c] = 50 * sum_s max_d (Q_b . P_c^T), fp16 MFMA.
// TRANSPOSED tile: A = P_c (m = d rows), B = Q_b (n = s cols).
// Wave w owns d-rows [w*32, w*32+32) (mtiles 2w,2w+1) x all 32 s (ntiles 0,1).
// max over d is then in-lane (regs+mtiles) + 2 quad-shuffles; sum over s in
// the epilogue. Per-b DS traffic: 4 shuffles + 1 ds_write (was 16 + 1).
// ---------------------------------------------------------------------------
__global__ __launch_bounds__(256, 2) void scores_kernel(const float* __restrict__ pos,
                                                        const _Float16* __restrict__ qs,
                                                        float* __restrict__ scores) {
  const int c    = blockIdx.x;
  const int tid  = threadIdx.x;
  const int w    = tid >> 6;
  const int lane = tid & 63;
  const int quad = lane >> 4;
  const int mrow = lane & 15;

  __shared__ float pmm[BQ][4][32];   // [b][wave][s]  16 KB

  const half8v* qf = (const half8v*)qs;
  const float*  pc = pos + (size_t)c * (D * H);

  half8v  pa[2][4];      // P_c A-frags [mt2][kb], register-resident (32 VGPRs)
  half8v  qb[2][2][4];   // Q B-frags, double-buffered [buf][nt][kb] (64 VGPRs)
  floatx4 acc[2][2][2];  // accumulators [buf][mt2][nt] (32 VGPRs)

  // Q fragments for b=0 and b=1:  index ((b*4+kb)*2 + nt)*64 + lane
#pragma unroll
  for (int nt = 0; nt < 2; ++nt)
#pragma unroll
    for (int kb = 0; kb < 4; ++kb) {
      qb[0][nt][kb] = qf[(kb * 2 + nt) * 64 + lane];
      qb[1][nt][kb] = qf[(( (1 * 4) + kb) * 2 + nt) * 64 + lane];
    }

  // P_c A-frags: A[m = w*32 + mt2*16 + (lane&15)][k = kb*32 + quad*8 + j]
#pragma unroll
  for (int kb = 0; kb < 4; ++kb)
#pragma unroll
    for (int mt2 = 0; mt2 < 2; ++mt2) {
      const float* src = pc + ((w * 32 + mt2 * 16 + mrow) * H + kb * 32 + quad * 8);
      float4 v0 = *(const float4*)src;
      float4 v1 = *(const float4*)(src + 4);
      half8v f = { (_Float16)v0.x, (_Float16)v0.y, (_Float16)v0.z, (_Float16)v0.w,
                   (_Float16)v1.x, (_Float16)v1.y, (_Float16)v1.z, (_Float16)v1.w };
      pa[mt2][kb] = f;
    }

  // Reduce one finished accumulator set: max over this wave's 32 d-rows.
  // C/D layout: row d_local = quad*4 + r (+ mt2*16), col s = nt*16 + (lane&15).
  auto reduce_store = [&](int b, floatx4 (&a)[2][2]) {
    float t0 = fmaxf(fmaxf(fmaxf(a[0][0][0], a[0][0][1]), fmaxf(a[0][0][2], a[0][0][3])),
                     fmaxf(fmaxf(a[1][0][0], a[1][0][1]), fmaxf(a[1][0][2], a[1][0][3])));
    float t1 = fmaxf(fmaxf(fmaxf(a[0][1][0], a[0][1][1]), fmaxf(a[0][1][2], a[0][1][3])),
                     fmaxf(fmaxf(a[1][1][0], a[1][1][1]), fmaxf(a[1][1][2], a[1][1][3])));
    t0 = fmaxf(t0, __shfl_xor(t0, 16));
    t0 = fmaxf(t0, __shfl_xor(t0, 32));
    t1 = fmaxf(t1, __shfl_xor(t1, 16));
    t1 = fmaxf(t1, __shfl_xor(t1, 32));
    // lanes 0-15 hold s=lane (nt=0); lanes 16-31 write s=lane via t1 (nt=1)
    float v = (lane < 16) ? t0 : t1;
    if (lane < 32) pmm[b][w][lane] = v;
  };

  // b = 0 into acc[0]
#pragma unroll
  for (int mt2 = 0; mt2 < 2; ++mt2)
#pragma unroll
    for (int nt = 0; nt < 2; ++nt) { floatx4 z = {0.f, 0.f, 0.f, 0.f}; acc[0][mt2][nt] = z; }
#pragma unroll
  for (int kb = 0; kb < 4; ++kb)
#pragma unroll
    for (int mt2 = 0; mt2 < 2; ++mt2)
#pragma unroll
      for (int nt = 0; nt < 2; ++nt)
        acc[0][mt2][nt] = __builtin_amdgcn_mfma_f32_16x16x32_f16(
            pa[mt2][kb], qb[0][nt][kb], acc[0][mt2][nt], 0, 0, 0);

  // pipelined main loop: MFMAs for b overlap the (short) reduction of b-1
#pragma unroll
  for (int b = 1; b < BQ; ++b) {
    const int cur = b & 1, prv = cur ^ 1;
    if (b + 1 < BQ) {
#pragma unroll
      for (int nt = 0; nt < 2; ++nt)
#pragma unroll
        for (int kb = 0; kb < 4; ++kb)
          qb[prv][nt][kb] = qf[(((b + 1) * 4 + kb) * 2 + nt) * 64 + lane];
    }
#pragma unroll
    for (int mt2 = 0; mt2 < 2; ++mt2)
#pragma unroll
      for (int nt = 0; nt < 2; ++nt) { floatx4 z = {0.f, 0.f, 0.f, 0.f}; acc[cur][mt2][nt] = z; }
#pragma unroll
    for (int kb = 0; kb < 4; ++kb)
#pragma unroll
      for (int mt2 = 0; mt2 < 2; ++mt2)
#pragma unroll
        for (int nt = 0; nt < 2; ++nt)
          acc[cur][mt2][nt] = __builtin_amdgcn_mfma_f32_16x16x32_f16(
              pa[mt2][kb], qb[cur][nt][kb], acc[cur][mt2][nt], 0, 0, 0);
    reduce_store(b - 1, acc[prv]);
  }
  reduce_store(BQ - 1, acc[1]);   // b=31 landed in acc[31&1]

  __syncthreads();

  // epilogue: scores[b][c] = 50 * sum_s max_w pmm[b][w][s]
  {
    int b  = tid >> 3;
    int sq = tid & 7;
    float4 x0 = *(float4*)&pmm[b][0][sq * 4];
    float4 x1 = *(float4*)&pmm[b][1][sq * 4];
    float4 x2 = *(float4*)&pmm[b][2][sq * 4];
    float4 x3 = *(float4*)&pmm[b][3][sq * 4];
    float mx_x = fmaxf(fmaxf(x0.x, x1.x), fmaxf(x2.x, x3.x));
    float mx_y = fmaxf(fmaxf(x0.y, x1.y), fmaxf(x2.y, x3.y));
    float mx_z = fmaxf(fmaxf(x0.z, x1.z), fmaxf(x2.z, x3.z));
    float mx_w = fmaxf(fmaxf(x0.w, x1.w), fmaxf(x2.w, x3.w));
    float v = (mx_x + mx_y) + (mx_z + mx_w);
    v += __shfl_xor(v, 1);
    v += __shfl_xor(v, 2);
    v += __shfl_xor(v, 4);
    if (sq == 0) scores[b * C + c] = v * 50.0f;   // / TEMPERATURE
  }
}

// ---------------------------------------------------------------------------
// Kernel 2: one block per b; loss += (logsumexp_c - scores[b][0]) / 32
// ---------------------------------------------------------------------------
__global__ __launch_bounds__(256) void loss_kernel(const float* __restrict__ scores,
                                                   float* __restrict__ out) {
  __shared__ float red[8];
  const int b = blockIdx.x, tid = threadIdx.x, w = tid >> 6, lane = tid & 63;
  const float* row = scores + b * C;
  float x0 = row[tid], x1 = row[tid + 256];
  float mx = fmaxf(x0, x1);
#pragma unroll
  for (int off = 1; off < 64; off <<= 1) mx = fmaxf(mx, __shfl_xor(mx, off));
  if (lane == 0) red[w] = mx;
  __syncthreads();
  float bmax = fmaxf(fmaxf(red[0], red[1]), fmaxf(red[2], red[3]));
  float e = __expf(x0 - bmax) + __expf(x1 - bmax);
#pragma unroll
  for (int off = 1; off < 64; off <<= 1) e += __shfl_xor(e, off);
  if (lane == 0) red[4 + w] = e;
  __syncthreads();
  if (tid == 0) {
    float s = red[4] + red[5] + red[6] + red[7];
    atomicAdd(out, (bmax + __logf(s) - row[0]) * (1.0f / 32.0f));
  }
}

extern "C" void kernel_launch(void* const* d_in, const int* in_sizes, int n_in,
                              void* d_out, int out_size, void* d_ws, size_t ws_size,
                              hipStream_t stream) {
  const float* q = (const float*)d_in[0];   // [32,32,128] fp32
  const float* p = (const float*)d_in[1];   // [512,128,128] fp32
  float* scores  = (float*)d_ws;                              // 64 KB
  _Float16* qs   = (_Float16*)((char*)d_ws + 65536);          // 256 KB fp16 frags

  qprep_kernel<<<64, 256, 0, stream>>>(q, qs, (float*)d_out);
  scores_kernel<<<C, 256, 0, stream>>>(p, qs, scores);
  loss_kernel<<<32, 256, 0, stream>>>(scores, (float*)d_out);
}

// Round 5
// 96.424 us; speedup vs baseline: 1.6315x; 1.0005x over previous
//
#include <hip/hip_runtime.h>

#define BQ 32
#define H  128
#define C  512
#define D  128

typedef _Float16 half8v __attribute__((ext_vector_type(8)));
typedef float floatx16 __attribute__((ext_vector_type(16)));

// ---------------------------------------------------------------------------
// Kernel 0: Q fp32 -> fp16 fragments for the 32x32x16 MFMA B-operand, and zero
// the loss accumulator (d_out).
// Frag index (half8 units): (b*8 + kb)*64 + lane
//   elem[n = lane&31][k = kb*16 + (lane>>5)*8 + j]   (n = s, 32 s per frag)
// ---------------------------------------------------------------------------
__global__ __launch_bounds__(256) void qprep_kernel(const float* __restrict__ q,
                                                    _Float16* __restrict__ qs,
                                                    float* __restrict__ out) {
  int t = blockIdx.x * 256 + threadIdx.x;     // 0..16383, one half8 frag each
  if (t == 0) out[0] = 0.0f;
  int lane = t & 63;
  int kb   = (t >> 6) & 7;
  int b    = t >> 9;
  int s    = lane & 31;
  int h    = kb * 16 + (lane >> 5) * 8;
  const float* src = q + ((b * 32 + s) * H + h);
  float4 v0 = *(const float4*)src;
  float4 v1 = *(const float4*)(src + 4);
  half8v o = { (_Float16)v0.x, (_Float16)v0.y, (_Float16)v0.z, (_Float16)v0.w,
               (_Float16)v1.x, (_Float16)v1.y, (_Float16)v1.z, (_Float16)v1.w };
  *(half8v*)(qs + (size_t)t * 8) = o;
}

// ---------------------------------------------------------------------------
// Kernel 1: block c -> scores[b][c] = 50 * sum_s max_d (Q_b . P_c^T).
// 32x32x16 f16 MFMA, transposed tile: A = P_c (m = d), B = Q_b (n = s).
// Wave w owns d-rows [w*32, w*32+32) x all 32 s: ONE 32x32 tile, 8 MFMAs/b
// (single dependent K-chain, C input = persistent zero regs).
// Reduction per b: 15 in-lane v_max + 1 shfl_xor(32) + 1 ds_write.
// qb fragments triple-buffered (prefetch distance 2 covers L2 latency).
// ---------------------------------------------------------------------------
__global__ __launch_bounds__(256, 2) void scores_kernel(const float* __restrict__ pos,
                                                        const _Float16* __restrict__ qs,
                                                        float* __restrict__ scores) {
  const int c    = blockIdx.x;
  const int tid  = threadIdx.x;
  const int w    = tid >> 6;
  const int lane = tid & 63;
  const int mrow = lane & 31;          // d-row within tile / s-col in C
  const int khi  = (lane >> 5) * 8;    // k sub-offset

  __shared__ float pmm[BQ][4][32];     // [b][wave][s]  16 KB

  const half8v* qf = (const half8v*)qs;
  const float*  pc = pos + (size_t)c * (D * H);

  half8v   pa[8];        // P_c A-frags [kb]  (32 VGPRs, block-resident)
  half8v   qb[3][8];     // Q B-frags, triple-buffered [buf][kb] (96 VGPRs)
  floatx16 acc[2];       // double-buffered accumulators (32 VGPRs)

  // persistent zero C-operand (never overwritten -> no per-b acc zeroing)
  floatx16 zc;
#pragma unroll
  for (int i = 0; i < 16; ++i) zc[i] = 0.0f;

  // P_c A-frags: A[m = w*32 + mrow][k = kb*16 + khi + j]
#pragma unroll
  for (int kb = 0; kb < 8; ++kb) {
    const float* src = pc + ((w * 32 + mrow) * H + kb * 16 + khi);
    float4 v0 = *(const float4*)src;
    float4 v1 = *(const float4*)(src + 4);
    half8v f = { (_Float16)v0.x, (_Float16)v0.y, (_Float16)v0.z, (_Float16)v0.w,
                 (_Float16)v1.x, (_Float16)v1.y, (_Float16)v1.z, (_Float16)v1.w };
    pa[kb] = f;
  }

  // Q fragments for b=0, b=1
#pragma unroll
  for (int kb = 0; kb < 8; ++kb) qb[0][kb] = qf[kb * 64 + lane];
#pragma unroll
  for (int kb = 0; kb < 8; ++kb) qb[1][kb] = qf[(8 + kb) * 64 + lane];

  // Reduce: max over this wave's 32 d-rows for each s.
  // C/D: col s = lane&31, row d_local = (reg&3) + 8*(reg>>2) + 4*(lane>>5).
  auto reduce_store = [&](int b, floatx16& a) {
    float m01 = fmaxf(fmaxf(a[0],  a[1]),  fmaxf(a[2],  a[3]));
    float m23 = fmaxf(fmaxf(a[4],  a[5]),  fmaxf(a[6],  a[7]));
    float m45 = fmaxf(fmaxf(a[8],  a[9]),  fmaxf(a[10], a[11]));
    float m67 = fmaxf(fmaxf(a[12], a[13]), fmaxf(a[14], a[15]));
    float m = fmaxf(fmaxf(m01, m23), fmaxf(m45, m67));
    m = fmaxf(m, __shfl_xor(m, 32));   // combine the two half-row sets
    if (lane < 32) pmm[b][w][lane] = m;
  };

  // b = 0 into acc[0]
  acc[0] = __builtin_amdgcn_mfma_f32_32x32x16_f16(pa[0], qb[0][0], zc, 0, 0, 0);
#pragma unroll
  for (int kb = 1; kb < 8; ++kb)
    acc[0] = __builtin_amdgcn_mfma_f32_32x32x16_f16(pa[kb], qb[0][kb], acc[0], 0, 0, 0);

  // pipelined main loop
#pragma unroll
  for (int b = 1; b < BQ; ++b) {
    const int cur = b & 1, prv = cur ^ 1;
    if (b + 1 < BQ) {
      const int nb = (b + 1) * 8;
      half8v* dst = qb[(b + 1) % 3];
#pragma unroll
      for (int kb = 0; kb < 8; ++kb) dst[kb] = qf[(nb + kb) * 64 + lane];
    }
    const half8v* qc = qb[b % 3];
    acc[cur] = __builtin_amdgcn_mfma_f32_32x32x16_f16(pa[0], qc[0], zc, 0, 0, 0);
#pragma unroll
    for (int kb = 1; kb < 8; ++kb)
      acc[cur] = __builtin_amdgcn_mfma_f32_32x32x16_f16(pa[kb], qc[kb], acc[cur], 0, 0, 0);
    reduce_store(b - 1, acc[prv]);
  }
  reduce_store(BQ - 1, acc[1]);   // b=31 landed in acc[31&1]

  __syncthreads();

  // epilogue: scores[b][c] = 50 * sum_s max_w pmm[b][w][s]
  {
    int b  = tid >> 3;
    int sq = tid & 7;
    float4 x0 = *(float4*)&pmm[b][0][sq * 4];
    float4 x1 = *(float4*)&pmm[b][1][sq * 4];
    float4 x2 = *(float4*)&pmm[b][2][sq * 4];
    float4 x3 = *(float4*)&pmm[b][3][sq * 4];
    float mx_x = fmaxf(fmaxf(x0.x, x1.x), fmaxf(x2.x, x3.x));
    float mx_y = fmaxf(fmaxf(x0.y, x1.y), fmaxf(x2.y, x3.y));
    float mx_z = fmaxf(fmaxf(x0.z, x1.z), fmaxf(x2.z, x3.z));
    float mx_w = fmaxf(fmaxf(x0.w, x1.w), fmaxf(x2.w, x3.w));
    float v = (mx_x + mx_y) + (mx_z + mx_w);
    v += __shfl_xor(v, 1);
    v += __shfl_xor(v, 2);
    v += __shfl_xor(v, 4);
    if (sq == 0) scores[b * C + c] = v * 50.0f;   // / TEMPERATURE
  }
}

// ---------------------------------------------------------------------------
// Kernel 2: one block per b; loss += (logsumexp_c - scores[b][0]) / 32
// ---------------------------------------------------------------------------
__global__ __launch_bounds__(256) void loss_kernel(const float* __restrict__ scores,
                                                   float* __restrict__ out) {
  __shared__ float red[8];
  const int b = blockIdx.x, tid = threadIdx.x, w = tid >> 6, lane = tid & 63;
  const float* row = scores + b * C;
  float x0 = row[tid], x1 = row[tid + 256];
  float mx = fmaxf(x0, x1);
#pragma unroll
  for (int off = 1; off < 64; off <<= 1) mx = fmaxf(mx, __shfl_xor(mx, off));
  if (lane == 0) red[w] = mx;
  __syncthreads();
  float bmax = fmaxf(fmaxf(red[0], red[1]), fmaxf(red[2], red[3]));
  float e = __expf(x0 - bmax) + __expf(x1 - bmax);
#pragma unroll
  for (int off = 1; off < 64; off <<= 1) e += __shfl_xor(e, off);
  if (lane == 0) red[4 + w] = e;
  __syncthreads();
  if (tid == 0) {
    float s = red[4] + red[5] + red[6] + red[7];
    atomicAdd(out, (bmax + __logf(s) - row[0]) * (1.0f / 32.0f));
  }
}

extern "C" void kernel_launch(void* const* d_in, const int* in_sizes, int n_in,
                              void* d_out, int out_size, void* d_ws, size_t ws_size,
                              hipStream_t stream) {
  const float* q = (const float*)d_in[0];   // [32,32,128] fp32
  const float* p = (const float*)d_in[1];   // [512,128,128] fp32
  float* scores  = (float*)d_ws;                              // 64 KB
  _Float16* qs   = (_Float16*)((char*)d_ws + 65536);          // 256 KB fp16 frags

  qprep_kernel<<<64, 256, 0, stream>>>(q, qs, (float*)d_out);
  scores_kernel<<<C, 256, 0, stream>>>(p, qs, scores);
  loss_kernel<<<32, 256, 0, stream>>>(scores, (float*)d_out);
}